// Round 1
// baseline (12373.451 us; speedup 1.0000x reference)
//
#include <hip/hip_runtime.h>

// ---------------------------------------------------------------------------
// LSTM (T=512, B=64, D=1024) + log_softmax projection.
// Plan:
//   1) convert_x:  x fp32 -> Xb bf16                       [33.5M elems]
//   2) permute_w:  W_ih/W_hh fp32 -> bf16, rows permuted so block i owns
//                  gate columns {g*1024 + 4i + u} at pcol = 16i + 4u + g,
//                  biasP[pcol] = b_ih+b_hh
//   3) gemm_ih:    G[32768][4096] bf16 = Xb @ WihP^T + biasP   (MFMA 16x16x32)
//   4) lstm_persistent: 256 blocks (1/CU), W_hh slice in LDS (swizzled),
//                  per step: gates = h @ Whh^T (K split over 4 waves, LDS
//                  reduce) + G[t]; pointwise update; h double-buffered bf16;
//                  custom agent-scope grid barrier per step; block 0 does the
//                  final projection + log_softmax.
// ---------------------------------------------------------------------------

typedef float f32x4 __attribute__((ext_vector_type(4)));
typedef short bf16x8 __attribute__((ext_vector_type(8)));

#define T_STEPS 512
#define NBLK 256

__device__ inline unsigned short f2bf(float f) {
  unsigned u = __float_as_uint(f);
  u = u + 0x7FFFu + ((u >> 16) & 1u);
  return (unsigned short)(u >> 16);
}
__device__ inline float bf2f(unsigned short s) {
  return __uint_as_float(((unsigned)s) << 16);
}
__device__ inline float sigf(float x) { return 1.f / (1.f + __expf(-x)); }
__device__ inline float tanh_f(float x) {
  float e = __expf(-2.f * fabsf(x));
  float r = (1.f - e) / (1.f + e);
  return x >= 0.f ? r : -r;
}

// ---------------------------------------------------------------- convert_x
__global__ void convert_x(const float* __restrict__ x,
                          unsigned short* __restrict__ Xb, int n4) {
  int i = blockIdx.x * blockDim.x + threadIdx.x;
  const int stride = gridDim.x * blockDim.x;
  for (; i < n4; i += stride) {
    float4 v = ((const float4*)x)[i];
    ushort4 o;
    o.x = f2bf(v.x); o.y = f2bf(v.y); o.z = f2bf(v.z); o.w = f2bf(v.w);
    ((ushort4*)Xb)[i] = o;
  }
}

// ---------------------------------------------------------------- permute_w
// pcol = 16*i + 4*u + g  ->  orig row = g*1024 + 4*i + u
__global__ void permute_w(const float* __restrict__ Wih,
                          const float* __restrict__ Whh,
                          const float* __restrict__ bih,
                          const float* __restrict__ bhh,
                          unsigned short* __restrict__ WihP,
                          unsigned short* __restrict__ WhhP,
                          float* __restrict__ biasP) {
  const int p = blockIdx.x;
  const int i = p >> 4, u = (p >> 2) & 3, g = p & 3;
  const int orig = g * 1024 + i * 4 + u;
  const int k = threadIdx.x * 4;
  float4 a = *(const float4*)(Wih + (size_t)orig * 1024 + k);
  ushort4 oa; oa.x = f2bf(a.x); oa.y = f2bf(a.y); oa.z = f2bf(a.z); oa.w = f2bf(a.w);
  *(ushort4*)(WihP + (size_t)p * 1024 + k) = oa;
  float4 b = *(const float4*)(Whh + (size_t)orig * 1024 + k);
  ushort4 ob; ob.x = f2bf(b.x); ob.y = f2bf(b.y); ob.z = f2bf(b.z); ob.w = f2bf(b.w);
  *(ushort4*)(WhhP + (size_t)p * 1024 + k) = ob;
  if (threadIdx.x == 0) biasP[p] = bih[orig] + bhh[orig];
}

// ---------------------------------------------------------------- gemm_ih
// G[32768][4096] = Xb[32768][1024] @ WihP[4096][1024]^T + biasP
// 128x128 tile, BK=64, 4 waves 2x2, global_load_lds(16B) with source-side
// XOR swizzle (chunk ^= row&7) so ds_read_b128 frags are ~conflict-free.
__global__ __launch_bounds__(256, 2) void gemm_ih(
    const unsigned short* __restrict__ Xb,
    const unsigned short* __restrict__ WihP,
    const float* __restrict__ biasP,
    unsigned short* __restrict__ G) {
  __shared__ unsigned short Alds[128 * 64];
  __shared__ unsigned short Blds[128 * 64];
  const int tid = threadIdx.x, lane = tid & 63, wave = tid >> 6;
  const int mt = blockIdx.y, nt = blockIdx.x;
  const int wm = (wave >> 1) * 64, wn = (wave & 1) * 64;

  f32x4 acc[4][4];
  {
    f32x4 z = {0.f, 0.f, 0.f, 0.f};
#pragma unroll
    for (int m = 0; m < 4; ++m)
#pragma unroll
      for (int n = 0; n < 4; ++n) acc[m][n] = z;
  }

  const int srow = lane >> 3;               // 0..7 (row within 8-row stage)
  const int schunk = (lane & 7) ^ srow;     // source-side swizzle
  const int frow = lane & 15;
  const int kgrp = lane >> 4;

  for (int kt = 0; kt < 16; ++kt) {
    __syncthreads();
#pragma unroll
    for (int q = 0; q < 4; ++q) {
      const int rr = (wave * 4 + q) * 8 + srow;
      const unsigned short* ga =
          Xb + (size_t)(mt * 128 + rr) * 1024 + kt * 64 + schunk * 8;
      __builtin_amdgcn_global_load_lds(
          (const __attribute__((address_space(1))) void*)ga,
          (__attribute__((address_space(3))) void*)(Alds + (wave * 4 + q) * 512),
          16, 0, 0);
      const unsigned short* gb =
          WihP + (size_t)(nt * 128 + rr) * 1024 + kt * 64 + schunk * 8;
      __builtin_amdgcn_global_load_lds(
          (const __attribute__((address_space(1))) void*)gb,
          (__attribute__((address_space(3))) void*)(Blds + (wave * 4 + q) * 512),
          16, 0, 0);
    }
    __syncthreads();
#pragma unroll
    for (int kk = 0; kk < 2; ++kk) {
      bf16x8 av[4], bv[4];
      const int kb = kk * 32 + 8 * kgrp;
#pragma unroll
      for (int i = 0; i < 4; ++i) {
        const int ra = wm + 16 * i + frow;
        av[i] = *(const bf16x8*)(Alds + ra * 64 + (kb ^ ((ra & 7) << 3)));
        const int rb = wn + 16 * i + frow;
        bv[i] = *(const bf16x8*)(Blds + rb * 64 + (kb ^ ((rb & 7) << 3)));
      }
#pragma unroll
      for (int m = 0; m < 4; ++m)
#pragma unroll
        for (int n = 0; n < 4; ++n)
          acc[m][n] = __builtin_amdgcn_mfma_f32_16x16x32_bf16(
              av[m], bv[n], acc[m][n], 0, 0, 0);
    }
  }
  // epilogue: C row = (lane>>4)*4 + reg, col = lane&15 (m89-verified layout)
#pragma unroll
  for (int n = 0; n < 4; ++n) {
    const int col = nt * 128 + wn + 16 * n + frow;
    const float bvv = biasP[col];
#pragma unroll
    for (int m = 0; m < 4; ++m) {
      const int row0 = mt * 128 + wm + 16 * m + kgrp * 4;
#pragma unroll
      for (int r = 0; r < 4; ++r)
        G[(size_t)(row0 + r) * 4096 + col] = f2bf(acc[m][n][r] + bvv);
    }
  }
}

// ---------------------------------------------------------------- recurrence
__global__ __launch_bounds__(256, 2) void lstm_persistent(
    const unsigned short* __restrict__ G,     // [T*64][4096] bf16 (permuted)
    const unsigned short* __restrict__ WhhP,  // [4096][1024] bf16 (permuted)
    unsigned short* __restrict__ hbuf,        // 2 x [64][1024] bf16 (dbuf)
    float* __restrict__ hfinal,               // [64][1024] f32
    const float* __restrict__ Wproj,          // [2][1024]
    const float* __restrict__ bproj,          // [2]
    float* __restrict__ out,                  // [64][2]
    unsigned* __restrict__ syncb) {
  __shared__ unsigned short Wlds[16 * 1024];  // 32 KB, XOR-swizzled
  __shared__ float Glds[4 * 16 * 64];         // 16 KB partials [w][c][row^swz]
  const int tid = threadIdx.x, lane = tid & 63, wave = tid >> 6;
  const int bid = blockIdx.x;

  // Stage this block's Whh slice (rows 16*bid .. +15), swizzled:
  // elem (c,k) stored at c*1024 + (k ^ ((c&7)<<3)); 8-elem granular.
  {
    const int c = tid >> 4;
    const int k0 = (tid & 15) * 64;
#pragma unroll
    for (int j = 0; j < 64; j += 8) {
      const int k = k0 + j;
      uint4 v = *(const uint4*)(WhhP + (size_t)(bid * 16 + c) * 1024 + k);
      *(uint4*)(Wlds + c * 1024 + (k ^ ((c & 7) << 3))) = v;
    }
  }
  const int ub = tid >> 2, uu = tid & 3;  // update thread: batch ub, unit uu
  float c_state = 0.f;
  ushort4 gcur = *(const ushort4*)(G + (size_t)ub * 4096 + bid * 16 + uu * 4);
  __syncthreads();

  const int wbase = wave * 256;  // K range per wave
  const int frow = lane & 15;
  const int kgrp = lane >> 4;
  const int bswz = (frow & 7) << 3;

  for (int t = 0; t < T_STEPS; ++t) {
    ushort4 gnext = gcur;
    if (t + 1 < T_STEPS)
      gnext = *(const ushort4*)(G + (size_t)((t + 1) * 64 + ub) * 4096 +
                                bid * 16 + uu * 4);
    const unsigned short* hread = hbuf + (size_t)(t & 1) * 65536;
    unsigned short* hwrite = hbuf + (size_t)((t + 1) & 1) * 65536;

    f32x4 acc[4];
    {
      f32x4 z = {0.f, 0.f, 0.f, 0.f};
      acc[0] = z; acc[1] = z; acc[2] = z; acc[3] = z;
    }
#pragma unroll
    for (int half = 0; half < 2; ++half) {
      bf16x8 bfr[4];
      bf16x8 afr[4][4];
#pragma unroll
      for (int kw = 0; kw < 4; ++kw) {
        const int k = wbase + (half * 4 + kw) * 32 + 8 * kgrp;
        bfr[kw] = *(const bf16x8*)(Wlds + frow * 1024 + (k ^ bswz));
#pragma unroll
        for (int m = 0; m < 4; ++m)
          afr[kw][m] =
              *(const bf16x8*)(hread + (size_t)(16 * m + frow) * 1024 + k);
      }
#pragma unroll
      for (int kw = 0; kw < 4; ++kw)
#pragma unroll
        for (int m = 0; m < 4; ++m)
          acc[m] = __builtin_amdgcn_mfma_f32_16x16x32_bf16(afr[kw][m], bfr[kw],
                                                           acc[m], 0, 0, 0);
    }
    // write K-partials: Glds[wave][c= frow][row ^ ((c&7)<<2)]
    {
      const int swz = (frow & 7) << 2;
      float* gp = Glds + wave * 1024 + frow * 64;
#pragma unroll
      for (int m = 0; m < 4; ++m) {
        const int row = 16 * m + 4 * kgrp;
        *(f32x4*)(gp + (row ^ swz)) = acc[m];
      }
    }
    __syncthreads();
    // pointwise update: thread (ub,uu); gates c = uu*4 + g (g = i,f,g,o)
    {
      float gv[4];
#pragma unroll
      for (int g = 0; g < 4; ++g) {
        const int c = uu * 4 + g;
        const int idx = c * 64 + (ub ^ ((c & 7) << 2));
        float s = Glds[idx] + Glds[1024 + idx] + Glds[2048 + idx] +
                  Glds[3072 + idx];
        const unsigned short* gc = (const unsigned short*)&gcur;
        gv[g] = s + bf2f(gc[g]);
      }
      const float ig = sigf(gv[0]);
      const float fg = sigf(gv[1]);
      const float gg = tanh_f(gv[2]);
      const float og = sigf(gv[3]);
      c_state = fg * c_state + ig * gg;
      const float hv = og * tanh_f(c_state);
      hwrite[(size_t)ub * 1024 + bid * 4 + uu] = f2bf(hv);
      if (t == T_STEPS - 1) hfinal[(size_t)ub * 1024 + bid * 4 + uu] = hv;
      gcur = gnext;
    }
    __syncthreads();
    // grid barrier: 8 sub-counters -> master; monotonic, no reset.
    if (tid == 0) {
      __threadfence();
      const unsigned target = (unsigned)(t + 1);
      unsigned v = __hip_atomic_fetch_add(&syncb[(bid & 7) * 32], 1u,
                                          __ATOMIC_ACQ_REL,
                                          __HIP_MEMORY_SCOPE_AGENT);
      if (v == 32u * target - 1u)
        __hip_atomic_fetch_add(&syncb[256], 1u, __ATOMIC_ACQ_REL,
                               __HIP_MEMORY_SCOPE_AGENT);
      unsigned guard = 0;
      while (__hip_atomic_load(&syncb[256], __ATOMIC_ACQUIRE,
                               __HIP_MEMORY_SCOPE_AGENT) < 8u * target) {
        __builtin_amdgcn_s_sleep(8);
        if (++guard > (1u << 18)) break;  // liveness escape (never in normal run)
      }
    }
    __syncthreads();
  }

  // projection + log_softmax (block 0)
  if (bid == 0 && tid < 128) {
    const int b = tid >> 1, cls = tid & 1;
    const float* hf = hfinal + (size_t)b * 1024;
    const float* wp = Wproj + (size_t)cls * 1024;
    float s = bproj[cls];
    for (int k = 0; k < 1024; k += 4) {
      float4 hv4 = *(const float4*)(hf + k);
      float4 wv4 = *(const float4*)(wp + k);
      s += hv4.x * wv4.x + hv4.y * wv4.y + hv4.z * wv4.z + hv4.w * wv4.w;
    }
    const float other = __shfl_xor(s, 1);
    const float mx = fmaxf(s, other);
    const float lse = mx + logf(expf(s - mx) + expf(other - mx));
    out[tid] = s - lse;
  }
}

// ---------------------------------------------------------------- launcher
extern "C" void kernel_launch(void* const* d_in, const int* in_sizes, int n_in,
                              void* d_out, int out_size, void* d_ws,
                              size_t ws_size, hipStream_t stream) {
  const float* x = (const float*)d_in[0];
  const float* Wih = (const float*)d_in[1];
  const float* Whh = (const float*)d_in[2];
  const float* bih = (const float*)d_in[3];
  const float* bhh = (const float*)d_in[4];
  const float* Wproj = (const float*)d_in[5];
  const float* bproj = (const float*)d_in[6];
  float* out = (float*)d_out;

  // workspace layout (bytes)
  const size_t OFF_G = 0;                           // 268435456
  const size_t OFF_XB = 268435456;                  // 67108864
  const size_t OFF_WIH = 335544320;                 // 8388608
  const size_t OFF_WHH = 343932928;                 // 8388608
  const size_t OFF_BIAS = 352321536;                // 16384
  const size_t OFF_H = 352337920;                   // 262144 (double buffer)
  const size_t OFF_HF = 352600064;                  // 262144
  const size_t OFF_SYNC = 352862208;                // 4096
  const size_t TOTAL = 352866304;

  if (ws_size < TOTAL) {  // clean, detectable failure path
    hipMemsetAsync(d_out, 0, (size_t)out_size * sizeof(float), stream);
    return;
  }
  char* ws = (char*)d_ws;
  unsigned short* G = (unsigned short*)(ws + OFF_G);
  unsigned short* Xb = (unsigned short*)(ws + OFF_XB);
  unsigned short* WihP = (unsigned short*)(ws + OFF_WIH);
  unsigned short* WhhP = (unsigned short*)(ws + OFF_WHH);
  float* biasP = (float*)(ws + OFF_BIAS);
  unsigned short* hbuf = (unsigned short*)(ws + OFF_H);
  float* hfinal = (float*)(ws + OFF_HF);
  unsigned* syncb = (unsigned*)(ws + OFF_SYNC);

  hipMemsetAsync(hbuf, 0, 262144, stream);
  hipMemsetAsync(syncb, 0, 4096, stream);

  convert_x<<<2048, 256, 0, stream>>>(x, Xb, 512 * 64 * 1024 / 4);
  permute_w<<<4096, 256, 0, stream>>>(Wih, Whh, bih, bhh, WihP, WhhP, biasP);
  gemm_ih<<<dim3(32, 256), 256, 0, stream>>>(Xb, WihP, biasP, G);
  lstm_persistent<<<NBLK, 256, 0, stream>>>(G, WhhP, hbuf, hfinal, Wproj,
                                            bproj, out, syncb);
}

// Round 3
// 3846.539 us; speedup vs baseline: 3.2168x; 3.2168x over previous
//
#include <hip/hip_runtime.h>

// ---------------------------------------------------------------------------
// LSTM (T=512, B=64, D=1024) + log_softmax projection.
//   1) convert_x:  x fp32 -> bf16
//   2) permute_w:  W_ih/W_hh -> bf16, gate-interleaved permutation
//   3) gemm_ih:    G[32768][4096] = Xb @ WihP^T + biasP  (MFMA, 128x128 tile)
//   4) lstm_grouped: P=4 batch-groups x C=64 col-blocks. Per-step barrier is
//      64-block flag quorum (agent-scope atomics); h exchange via agent-scope
//      relaxed atomic stores/loads (L3-coherent, no wbl2/inv in the loop).
//      W_hh slice (128 KB) LDS-resident, swizzled.
// ---------------------------------------------------------------------------

typedef float f32x4 __attribute__((ext_vector_type(4)));
typedef short bf16x8 __attribute__((ext_vector_type(8)));
typedef unsigned long long u64;

#define T_STEPS 512

__device__ inline unsigned short f2bf(float f) {
  unsigned u = __float_as_uint(f);
  u = u + 0x7FFFu + ((u >> 16) & 1u);
  return (unsigned short)(u >> 16);
}
__device__ inline float bf2f(unsigned short s) {
  return __uint_as_float(((unsigned)s) << 16);
}
__device__ inline float sigf(float x) { return 1.f / (1.f + __expf(-x)); }
__device__ inline float tanh_f(float x) {
  float e = __expf(-2.f * fabsf(x));
  float r = (1.f - e) / (1.f + e);
  return x >= 0.f ? r : -r;
}

// ---------------------------------------------------------------- convert_x
__global__ void convert_x(const float* __restrict__ x,
                          unsigned short* __restrict__ Xb, int n4) {
  int i = blockIdx.x * blockDim.x + threadIdx.x;
  const int stride = gridDim.x * blockDim.x;
  for (; i < n4; i += stride) {
    float4 v = ((const float4*)x)[i];
    ushort4 o;
    o.x = f2bf(v.x); o.y = f2bf(v.y); o.z = f2bf(v.z); o.w = f2bf(v.w);
    ((ushort4*)Xb)[i] = o;
  }
}

// ---------------------------------------------------------------- permute_w
// pcol = 16*i + 4*u + g  ->  orig row = g*1024 + 4*i + u   (unit = 4i+u)
__global__ void permute_w(const float* __restrict__ Wih,
                          const float* __restrict__ Whh,
                          const float* __restrict__ bih,
                          const float* __restrict__ bhh,
                          unsigned short* __restrict__ WihP,
                          unsigned short* __restrict__ WhhP,
                          float* __restrict__ biasP) {
  const int p = blockIdx.x;
  const int i = p >> 4, u = (p >> 2) & 3, g = p & 3;
  const int orig = g * 1024 + i * 4 + u;
  const int k = threadIdx.x * 4;
  float4 a = *(const float4*)(Wih + (size_t)orig * 1024 + k);
  ushort4 oa; oa.x = f2bf(a.x); oa.y = f2bf(a.y); oa.z = f2bf(a.z); oa.w = f2bf(a.w);
  *(ushort4*)(WihP + (size_t)p * 1024 + k) = oa;
  float4 b = *(const float4*)(Whh + (size_t)orig * 1024 + k);
  ushort4 ob; ob.x = f2bf(b.x); ob.y = f2bf(b.y); ob.z = f2bf(b.z); ob.w = f2bf(b.w);
  *(ushort4*)(WhhP + (size_t)p * 1024 + k) = ob;
  if (threadIdx.x == 0) biasP[p] = bih[orig] + bhh[orig];
}

// ---------------------------------------------------------------- gemm_ih
__global__ __launch_bounds__(256, 2) void gemm_ih(
    const unsigned short* __restrict__ Xb,
    const unsigned short* __restrict__ WihP,
    const float* __restrict__ biasP,
    unsigned short* __restrict__ G) {
  __shared__ unsigned short Alds[128 * 64];
  __shared__ unsigned short Blds[128 * 64];
  const int tid = threadIdx.x, lane = tid & 63, wave = tid >> 6;
  const int mt = blockIdx.y, nt = blockIdx.x;
  const int wm = (wave >> 1) * 64, wn = (wave & 1) * 64;

  f32x4 acc[4][4];
  {
    f32x4 z = {0.f, 0.f, 0.f, 0.f};
#pragma unroll
    for (int m = 0; m < 4; ++m)
#pragma unroll
      for (int n = 0; n < 4; ++n) acc[m][n] = z;
  }

  const int srow = lane >> 3;
  const int schunk = (lane & 7) ^ srow;
  const int frow = lane & 15;
  const int kgrp = lane >> 4;

  for (int kt = 0; kt < 16; ++kt) {
    __syncthreads();
#pragma unroll
    for (int q = 0; q < 4; ++q) {
      const int rr = (wave * 4 + q) * 8 + srow;
      const unsigned short* ga =
          Xb + (size_t)(mt * 128 + rr) * 1024 + kt * 64 + schunk * 8;
      __builtin_amdgcn_global_load_lds(
          (const __attribute__((address_space(1))) void*)ga,
          (__attribute__((address_space(3))) void*)(Alds + (wave * 4 + q) * 512),
          16, 0, 0);
      const unsigned short* gb =
          WihP + (size_t)(nt * 128 + rr) * 1024 + kt * 64 + schunk * 8;
      __builtin_amdgcn_global_load_lds(
          (const __attribute__((address_space(1))) void*)gb,
          (__attribute__((address_space(3))) void*)(Blds + (wave * 4 + q) * 512),
          16, 0, 0);
    }
    __syncthreads();
#pragma unroll
    for (int kk = 0; kk < 2; ++kk) {
      bf16x8 av[4], bv[4];
      const int kb = kk * 32 + 8 * kgrp;
#pragma unroll
      for (int i = 0; i < 4; ++i) {
        const int ra = wm + 16 * i + frow;
        av[i] = *(const bf16x8*)(Alds + ra * 64 + (kb ^ ((ra & 7) << 3)));
        const int rb = wn + 16 * i + frow;
        bv[i] = *(const bf16x8*)(Blds + rb * 64 + (kb ^ ((rb & 7) << 3)));
      }
#pragma unroll
      for (int m = 0; m < 4; ++m)
#pragma unroll
        for (int n = 0; n < 4; ++n)
          acc[m][n] = __builtin_amdgcn_mfma_f32_16x16x32_bf16(
              av[m], bv[n], acc[m][n], 0, 0, 0);
    }
  }
#pragma unroll
  for (int n = 0; n < 4; ++n) {
    const int col = nt * 128 + wn + 16 * n + frow;
    const float bvv = biasP[col];
#pragma unroll
    for (int m = 0; m < 4; ++m) {
      const int row0 = mt * 128 + wm + 16 * m + kgrp * 4;
#pragma unroll
      for (int r = 0; r < 4; ++r)
        G[(size_t)(row0 + r) * 4096 + col] = f2bf(acc[m][n][r] + bvv);
    }
  }
}

// ---------------------------------------------------------------- recurrence
// Grid: 256 blocks = 4 batch-groups (p = bid>>6) x 64 col-blocks (c = bid&63).
// Block (p,c): batches [16p,16p+16), gate pcols [64c,64c+64) = units
// [16c,16c+16). Per-step sync: 64 flags per group, quorum poll by wave 0.
__global__ __launch_bounds__(256, 1) void lstm_grouped(
    const unsigned short* __restrict__ G,     // [T*64][4096] bf16 (permuted)
    const unsigned short* __restrict__ WhhP,  // [4096][1024] bf16 (permuted)
    unsigned short* __restrict__ hbuf,        // 2 x [64][1024] bf16
    float* __restrict__ hfinal,               // [64][1024] f32
    const float* __restrict__ Wproj, const float* __restrict__ bproj,
    float* __restrict__ out,                  // [64][2]
    unsigned* __restrict__ flags) {           // [4][64]
  __shared__ unsigned short Wlds[64 * 1024];  // 128 KB, XOR-swizzled
  __shared__ float Glds[4 * 64 * 20];         // 20 KB K-partials, padded
  __shared__ unsigned short Hlds[16 * 16];    // h tile staging
  const int tid = threadIdx.x, lane = tid & 63, wave = tid >> 6;
  const int bid = blockIdx.x;
  const int p = bid >> 6, c = bid & 63;

  // stage W_hh slice, swizzled: elem (r,k) -> Wlds[r*1024 + (k ^ ((r&7)<<3))]
  {
    const int r = tid >> 2, q = tid & 3;
    const unsigned short* src = WhhP + (size_t)(c * 64 + r) * 1024 + q * 256;
    unsigned short* dstb = Wlds + r * 1024;
    const int swz = (r & 7) << 3;
#pragma unroll
    for (int j = 0; j < 256; j += 8) {
      uint4 v = *(const uint4*)(src + j);
      *(uint4*)(dstb + ((q * 256 + j) ^ swz)) = v;
    }
  }

  const int ub = tid >> 4, uu = tid & 15;           // update: batch, unit
  const int lpb = 16 * (uu >> 2) + 4 * (uu & 3);    // local pcol base (g=0)
  const int frow = lane & 15, kgrp = lane >> 4;
  const int wbase = wave * 256;                      // K split across waves
  float c_state = 0.f;
  ushort4 gcur =
      *(const ushort4*)(G + (size_t)(p * 16 + ub) * 4096 + c * 64 + lpb);
  __syncthreads();

  for (int t = 0; t < T_STEPS; ++t) {
    const unsigned short* hread = hbuf + (size_t)(t & 1) * 65536;
    unsigned short* hwrite = hbuf + (size_t)((t + 1) & 1) * 65536;

    // 1. quorum poll: all 64 flags of this group >= t  (h(t) published)
    if (wave == 0) {
      const unsigned* fl = flags + p * 64;
      unsigned guard = 0;
      while (true) {
        unsigned v = __hip_atomic_load(fl + lane, __ATOMIC_RELAXED,
                                       __HIP_MEMORY_SCOPE_AGENT);
        if (__all(v >= (unsigned)t)) break;
        if (++guard > (1u << 22)) break;  // liveness escape
      }
    }
    __syncthreads();

    // 2. prefetch next-step G (cached; G immutable)
    ushort4 gnext = gcur;
    if (t + 1 < T_STEPS)
      gnext = *(const ushort4*)(G + (size_t)((t + 1) * 64 + p * 16 + ub) * 4096 +
                                c * 64 + lpb);

    // 3. A (h) coherent loads + W frags + MFMA.  16 batches x 64 pcols,
    //    K=256 per wave.
    f32x4 acc[4];
    {
      f32x4 z = {0.f, 0.f, 0.f, 0.f};
      acc[0] = z; acc[1] = z; acc[2] = z; acc[3] = z;
    }
    bf16x8 av[8];
    {
      const unsigned short* abase =
          hread + (size_t)(p * 16 + frow) * 1024 + wbase + 8 * kgrp;
#pragma unroll
      for (int kw = 0; kw < 8; ++kw) {
        u64 lo = __hip_atomic_load((const u64*)(abase + kw * 32),
                                   __ATOMIC_RELAXED, __HIP_MEMORY_SCOPE_AGENT);
        u64 hi = __hip_atomic_load((const u64*)(abase + kw * 32 + 4),
                                   __ATOMIC_RELAXED, __HIP_MEMORY_SCOPE_AGENT);
        union { u64 q[2]; bf16x8 v; } uq;
        uq.q[0] = lo; uq.q[1] = hi;
        av[kw] = uq.v;
      }
    }
#pragma unroll
    for (int kw = 0; kw < 8; ++kw) {
      const int k = wbase + kw * 32 + 8 * kgrp;
#pragma unroll
      for (int n = 0; n < 4; ++n) {
        const int pcol = n * 16 + frow;
        bf16x8 bv =
            *(const bf16x8*)(Wlds + pcol * 1024 + (k ^ ((pcol & 7) << 3)));
        acc[n] = __builtin_amdgcn_mfma_f32_16x16x32_bf16(av[kw], bv, acc[n],
                                                         0, 0, 0);
      }
    }
    // 4. K-partials to LDS: Glds[wave][pcol][batch(+pad)]
    {
      float* gp = Glds + wave * 1280;
#pragma unroll
      for (int n = 0; n < 4; ++n)
        *(f32x4*)(gp + (n * 16 + frow) * 20 + 4 * kgrp) = acc[n];
    }
    __syncthreads();

    // 5. reduce + pointwise (thread = batch ub x unit uu)
    {
      float gv[4];
      const unsigned short* gc = (const unsigned short*)&gcur;
#pragma unroll
      for (int g = 0; g < 4; ++g) {
        const int idx = (lpb + g) * 20 + ub;
        gv[g] = Glds[idx] + Glds[1280 + idx] + Glds[2560 + idx] +
                Glds[3840 + idx] + bf2f(gc[g]);
      }
      const float ig = sigf(gv[0]);
      const float fg = sigf(gv[1]);
      const float gg = tanh_f(gv[2]);
      const float og = sigf(gv[3]);
      c_state = fg * c_state + ig * gg;
      const float hv = og * tanh_f(c_state);
      Hlds[ub * 16 + uu] = f2bf(hv);
      if (t == T_STEPS - 1) {
        float* dst = hfinal + (size_t)(p * 16 + ub) * 1024 + c * 16 + uu;
        __hip_atomic_store((unsigned*)dst, __float_as_uint(hv),
                           __ATOMIC_RELAXED, __HIP_MEMORY_SCOPE_AGENT);
      }
      gcur = gnext;
    }
    __syncthreads();  // all waves drain vmcnt (incl. hfinal stores) at barrier

    // 6. publish h tile (wave 0): agent-scope atomic u64 stores (compiler
    //    emits coherent store), wave-wide vmcnt(0) = release, then flag.
    if (wave == 0) {
      const int r = lane >> 2, q = lane & 3;
      u64 hq = *(const u64*)(Hlds + r * 16 + q * 4);
      u64* dst =
          (u64*)(hwrite + (size_t)(p * 16 + r) * 1024 + c * 16 + q * 4);
      __hip_atomic_store(dst, hq, __ATOMIC_RELAXED, __HIP_MEMORY_SCOPE_AGENT);
      asm volatile("s_waitcnt vmcnt(0)" ::: "memory");
      if (lane == 0)
        __hip_atomic_store(flags + p * 64 + c, (unsigned)(t + 1),
                           __ATOMIC_RELAXED, __HIP_MEMORY_SCOPE_AGENT);
    }
  }

  // ------------------------------------------------ projection (c==0 blocks)
  if (c == 0) {
    if (wave == 0) {
      const unsigned* fl = flags + p * 64;
      unsigned guard = 0;
      while (true) {
        unsigned v = __hip_atomic_load(fl + lane, __ATOMIC_RELAXED,
                                       __HIP_MEMORY_SCOPE_AGENT);
        if (__all(v >= (unsigned)T_STEPS)) break;
        if (++guard > (1u << 22)) break;
      }
    }
    __syncthreads();
    const int b = tid >> 4, seg = tid & 15;
    const float* hf = hfinal + (size_t)(p * 16 + b) * 1024 + seg * 64;
    const float* w0 = Wproj + seg * 64;
    const float* w1 = Wproj + 1024 + seg * 64;
    float s0 = 0.f, s1 = 0.f;
    for (int k = 0; k < 64; k += 2) {
      u64 hq = __hip_atomic_load((const u64*)(hf + k), __ATOMIC_RELAXED,
                                 __HIP_MEMORY_SCOPE_AGENT);
      union { u64 q; float f[2]; } uh;
      uh.q = hq;
      float2 wv0 = *(const float2*)(w0 + k);
      float2 wv1 = *(const float2*)(w1 + k);
      s0 += uh.f[0] * wv0.x + uh.f[1] * wv0.y;
      s1 += uh.f[0] * wv1.x + uh.f[1] * wv1.y;
    }
#pragma unroll
    for (int off = 8; off > 0; off >>= 1) {
      s0 += __shfl_down(s0, off, 16);
      s1 += __shfl_down(s1, off, 16);
    }
    if (seg == 0) {
      s0 += bproj[0];
      s1 += bproj[1];
      const float mx = fmaxf(s0, s1);
      const float lse = mx + logf(expf(s0 - mx) + expf(s1 - mx));
      out[(p * 16 + b) * 2 + 0] = s0 - lse;
      out[(p * 16 + b) * 2 + 1] = s1 - lse;
    }
  }
}

// ---------------------------------------------------------------- launcher
extern "C" void kernel_launch(void* const* d_in, const int* in_sizes, int n_in,
                              void* d_out, int out_size, void* d_ws,
                              size_t ws_size, hipStream_t stream) {
  const float* x = (const float*)d_in[0];
  const float* Wih = (const float*)d_in[1];
  const float* Whh = (const float*)d_in[2];
  const float* bih = (const float*)d_in[3];
  const float* bhh = (const float*)d_in[4];
  const float* Wproj = (const float*)d_in[5];
  const float* bproj = (const float*)d_in[6];
  float* out = (float*)d_out;

  const size_t OFF_G = 0;                  // 268435456
  const size_t OFF_XB = 268435456;         // 67108864
  const size_t OFF_WIH = 335544320;        // 8388608
  const size_t OFF_WHH = 343932928;        // 8388608
  const size_t OFF_BIAS = 352321536;       // 16384
  const size_t OFF_H = 352337920;          // 262144 (double buffer)
  const size_t OFF_HF = 352600064;         // 262144
  const size_t OFF_SYNC = 352862208;       // 4096
  const size_t TOTAL = 352866304;

  if (ws_size < TOTAL) {
    (void)hipMemsetAsync(d_out, 0, (size_t)out_size * sizeof(float), stream);
    return;
  }
  char* ws = (char*)d_ws;
  unsigned short* G = (unsigned short*)(ws + OFF_G);
  unsigned short* Xb = (unsigned short*)(ws + OFF_XB);
  unsigned short* WihP = (unsigned short*)(ws + OFF_WIH);
  unsigned short* WhhP = (unsigned short*)(ws + OFF_WHH);
  float* biasP = (float*)(ws + OFF_BIAS);
  unsigned short* hbuf = (unsigned short*)(ws + OFF_H);
  float* hfinal = (float*)(ws + OFF_HF);
  unsigned* flags = (unsigned*)(ws + OFF_SYNC);

  (void)hipMemsetAsync(hbuf, 0, 262144, stream);
  (void)hipMemsetAsync(flags, 0, 4096, stream);

  convert_x<<<2048, 256, 0, stream>>>(x, Xb, 512 * 64 * 1024 / 4);
  permute_w<<<4096, 256, 0, stream>>>(Wih, Whh, bih, bhh, WihP, WhhP, biasP);
  gemm_ih<<<dim3(32, 256), 256, 0, stream>>>(Xb, WihP, biasP, G);
  lstm_grouped<<<256, 256, 0, stream>>>(G, WhhP, hbuf, hfinal, Wproj, bproj,
                                        out, flags);
}